// Round 5
// baseline (256.723 us; speedup 1.0000x reference)
//
#include <hip/hip_runtime.h>
#include <hip/hip_bf16.h>

// GCN layer: out[b,n,o] = dis[b,n] * sum_m adj[b,n,m] * dis[b,m] * (x[b,m,:]@W[o,:] + bias[o])
//
// R12: K3 retiled 64x128 (ctile split) -> 32x256 (full-o blocks). The ctile
// split loaded+converted every adj row TWICE (268 MB f32 L3 reads, 2x cvt
// VALU) for the same MFMA count; the stage phase is K3's critical path
// (R9: compute side already covered by the co-resident block). Now each adj
// row is staged once: A loads/cvt per thread halve, A L3 traffic 268->134 MB.
// B staging doubles per block (16 async gl_lds16/thread) but total B traffic
// is unchanged and issue is cheap. LDS 72 KB -> still 2 blocks/CU (144<=160).
// Accumulation order over (g,s,kstep) identical -> bit-identical output.
// K12 (fused degree+proj, R11) unchanged.

#define BATCH 8
#define NN    2048
#define DIN   256
#define DOUT  256
#define RTOT  (BATCH * NN)   // 16384
#define HP    (RTOT + 32)    // 16416 padded hT row stride (elems)

typedef short  bf16x8  __attribute__((ext_vector_type(8)));
typedef short  short4v __attribute__((ext_vector_type(4)));
typedef float  f32x4   __attribute__((ext_vector_type(4)));

__device__ __forceinline__ short f2bf(float f) {
    union { float f; unsigned u; } v; v.f = f;
    unsigned r = v.u + 0x7fffu + ((v.u >> 16) & 1u);   // RNE
    return (short)(r >> 16);
}

__device__ __forceinline__ void gl_lds16(const unsigned short* g, unsigned short* l) {
    __builtin_amdgcn_global_load_lds(
        (const __attribute__((address_space(1))) unsigned int*)g,
        (__attribute__((address_space(3))) unsigned int*)l, 16, 0, 0);
}

// ---------------- K12: blocks 0..255 = projection (no dis), 256.. = degrees ----------------
__global__ __launch_bounds__(256) void k_deg_proj(const float* __restrict__ adj,
                                                  const float* __restrict__ x,
                                                  const float* __restrict__ W,
                                                  const float* __restrict__ bias,
                                                  float* __restrict__ dis,
                                                  unsigned short* __restrict__ hT) {
    const int tid = threadIdx.x;

    if (blockIdx.x < 256) {
        // ---- projection part: hT[o, r] = bf16((x@W^T)[r,o] + b[o]), padded rows ----
        const int bid = blockIdx.x;
        const int mt  = bid >> 7;         // 0..1   (o-tile of 128)
        const int nt  = bid & 127;        // 0..127 (r-tile of 128)
        const int w = tid >> 6, lane = tid & 63;
        const int wr = w >> 1, wc = w & 1;
        const int l16 = lane & 15, quad = lane >> 4;

        __shared__ short As[128][32];
        __shared__ short Bs[128][32];

        f32x4 acc[4][4];
#pragma unroll
        for (int i = 0; i < 4; i++)
#pragma unroll
            for (int j = 0; j < 4; j++) acc[i][j] = (f32x4){0.f, 0.f, 0.f, 0.f};

        const float4* Wf4 = (const float4*)(W + (size_t)mt * 128 * DIN);
        const float4* Xf4 = (const float4*)(x + (size_t)nt * 128 * DIN);

        for (int kk = 0; kk < DIN / 32; kk++) {
            const int k0 = kk * 32;
            __syncthreads();
#pragma unroll
            for (int it = 0; it < 4; it++) {
                int idx = tid + it * 256;
                int r = idx >> 3, c = idx & 7;
                float4 va = Wf4[(size_t)r * (DIN / 4) + (k0 >> 2) + c];
                float4 vb = Xf4[(size_t)r * (DIN / 4) + (k0 >> 2) + c];
                short4v sa = { f2bf(va.x), f2bf(va.y), f2bf(va.z), f2bf(va.w) };
                short4v sb = { f2bf(vb.x), f2bf(vb.y), f2bf(vb.z), f2bf(vb.w) };
                *(short4v*)&As[r][c * 4] = sa;
                *(short4v*)&Bs[r][c * 4] = sb;
            }
            __syncthreads();
            bf16x8 af[4], bfv[4];
#pragma unroll
            for (int i = 0; i < 4; i++) af[i]  = *(bf16x8*)&As[wr * 64 + i * 16 + l16][quad * 8];
#pragma unroll
            for (int j = 0; j < 4; j++) bfv[j] = *(bf16x8*)&Bs[wc * 64 + j * 16 + l16][quad * 8];
#pragma unroll
            for (int i = 0; i < 4; i++)
#pragma unroll
                for (int j = 0; j < 4; j++)
                    acc[i][j] = __builtin_amdgcn_mfma_f32_16x16x32_bf16(af[i], bfv[j], acc[i][j], 0, 0, 0);
        }

#pragma unroll
        for (int i = 0; i < 4; i++) {
            const int orow_base = mt * 128 + wr * 64 + i * 16 + quad * 4;
#pragma unroll
            for (int r = 0; r < 4; r++) {
                const int orow = orow_base + r;
                const float bb = bias[orow];
#pragma unroll
                for (int j = 0; j < 4; j++) {
                    const int col = nt * 128 + wc * 64 + j * 16 + l16;
                    float v = acc[i][j][r] + bb;               // dis NOT folded here
                    hT[(size_t)orow * HP + col] = (unsigned short)f2bf(v);
                }
            }
        }
    } else {
        // ---- degree part: dis[row] = rsqrt(rowsum - diag); order identical to R10 ----
        const int row = blockIdx.x - 256;           // 0..16383
        const int n = row & (NN - 1);
        const float4* rp4 = (const float4*)(adj + (size_t)row * NN);

        float s = 0.f;
#pragma unroll
        for (int i = 0; i < 2; i++) {
            float4 v = rp4[tid + i * 256];
            s += (v.x + v.y) + (v.z + v.w);
        }
#pragma unroll
        for (int off = 32; off; off >>= 1) s += __shfl_down(s, off);
        __shared__ float red[4];
        if ((tid & 63) == 0) red[tid >> 6] = s;
        __syncthreads();
        if (tid == 0) {
            float tot  = (red[0] + red[1]) + (red[2] + red[3]);
            float diag = ((const float*)rp4)[n];
            dis[row]   = rsqrtf(tot - diag);
        }
    }
}

// ---------------- K3: out = dis[n] * ((adj .* dis_m) @ hT), 32x256 tile, BK=128 ----------------
// Per batch: M=2048(n), K=2048(m), N=256(o, full width per block). Grid 512 =
// 8 batches x 64 mtiles; bx&7=batch (XCD L2 affinity for hT slice), bx>>3=mtile.
// 2 blocks/CU (LDS 72 KB). Per group: 16 async gl_lds16 (B), 4 float4 A + 4
// float4 dis -> fold in f32 -> RNE -> 8B ds_write; one drain; 32 MFMA/wave.
__global__ __launch_bounds__(256, 2) void k_main(const float* __restrict__ adj,
                                                 const unsigned short* __restrict__ hT,
                                                 const float* __restrict__ dis,
                                                 float* __restrict__ out) {
    const int bx    = blockIdx.x;
    const int b     = bx & 7;
    const int mtile = bx >> 3;            // 0..63
    const int n0    = mtile * 32;
    const int tid  = threadIdx.x;
    const int w    = tid >> 6, lane = tid & 63;
    const int l16  = lane & 15, quad = lane >> 4;
    const int lr   = lane >> 2;           // 0..15 (B staging row-within-chunk)
    const int lc   = (lane & 3) * 8;      // 0,8,16,24 (B staging elem offset)
    const int ar   = tid >> 3;            // 0..31 (A staging row)
    const int ac   = (tid & 7) * 4;       // 0..28 (A staging elem offset)

    __shared__ short As[4][32][32];       //  8 KB: 4 sub-windows of adj rows(n) x 32k
    __shared__ short Bs[4][256][32];      // 64 KB: 4 sub-windows of hT rows(o) x 32k

    const float* disb = dis + (size_t)b * NN;
    // A source: adj row (b*NN + n0 + ar); float4 index (g*128 + s*32 + ac)/4 = g*32+s*8+(tid&7)
    const float4* agf4 = (const float4*)(adj + (size_t)(b * NN + n0 + ar) * NN);
    // B source: hT row (w*16 + i*64 + lr), elem b*NN + g*128 + s*32 + lc
    const unsigned short* bgp = hT + (size_t)(w * 16 + lr) * HP + b * NN + lc;

    f32x4 acc[2][4];
#pragma unroll
    for (int i = 0; i < 2; i++)
#pragma unroll
        for (int j = 0; j < 4; j++) acc[i][j] = (f32x4){0.f, 0.f, 0.f, 0.f};

    for (int g = 0; g < NN / 128; g++) {          // 16 groups
        // B: 16 async gl_lds16 per thread (issue first, fly during A path)
#pragma unroll
        for (int s = 0; s < 4; s++) {
            const int ko = g * 128 + s * 32;
#pragma unroll
            for (int i = 0; i < 4; i++)
                gl_lds16(bgp + (size_t)i * 64 * HP + ko,
                         (unsigned short*)&Bs[s][w * 16 + i * 64][0]);
        }
        // A: 4 float4 adj (L3-hot) + 4 float4 dis (L1-hot) -> fold -> RNE -> 8B ds_write
        float4 av[4], dv[4];
#pragma unroll
        for (int s = 0; s < 4; s++) av[s] = agf4[g * 32 + s * 8 + (tid & 7)];
#pragma unroll
        for (int s = 0; s < 4; s++) dv[s] = *(const float4*)(disb + g * 128 + s * 32 + ac);
#pragma unroll
        for (int s = 0; s < 4; s++) {
            short4v pk = { f2bf(av[s].x * dv[s].x), f2bf(av[s].y * dv[s].y),
                           f2bf(av[s].z * dv[s].z), f2bf(av[s].w * dv[s].w) };
            *(short4v*)&As[s][ar][ac] = pk;
        }
        __syncthreads();   // drain staging once per 128-K of work
        // Consume: 32 MFMA + 24 ds_read_b128 per wave.
#pragma unroll
        for (int s = 0; s < 4; s++) {
            bf16x8 af[2], bfv[4];
#pragma unroll
            for (int i = 0; i < 2; i++) af[i]  = *(bf16x8*)&As[s][i * 16 + l16][quad * 8];
#pragma unroll
            for (int j = 0; j < 4; j++) bfv[j] = *(bf16x8*)&Bs[s][w * 64 + j * 16 + l16][quad * 8];
#pragma unroll
            for (int i = 0; i < 2; i++)
#pragma unroll
                for (int j = 0; j < 4; j++)
                    acc[i][j] = __builtin_amdgcn_mfma_f32_16x16x32_bf16(af[i], bfv[j], acc[i][j], 0, 0, 0);
        }
        __syncthreads();   // all ds_reads retired before restage
    }

#pragma unroll
    for (int i = 0; i < 2; i++) {
#pragma unroll
        for (int r = 0; r < 4; r++) {
            const int nrow = n0 + i * 16 + quad * 4 + r;
            const float dn = disb[nrow];
#pragma unroll
            for (int j = 0; j < 4; j++) {
                const int ocol = w * 64 + j * 16 + l16;
                out[((size_t)b * NN + nrow) * DOUT + ocol] = dn * acc[i][j][r];
            }
        }
    }
}

extern "C" void kernel_launch(void* const* d_in, const int* in_sizes, int n_in,
                              void* d_out, int out_size, void* d_ws, size_t ws_size,
                              hipStream_t stream) {
    const float* x    = (const float*)d_in[0];
    const float* adj  = (const float*)d_in[1];
    const float* W    = (const float*)d_in[2];
    const float* bias = (const float*)d_in[3];
    float* out = (float*)d_out;

    float* dis = (float*)d_ws;                                             // 64 KB
    unsigned short* hT  = (unsigned short*)((char*)d_ws + 65536);          // 256*16416*2 = 8.4 MB

    k_deg_proj<<<256 + RTOT, 256, 0, stream>>>(adj, x, W, bias, dis, hT);
    k_main<<<512, 256, 0, stream>>>(adj, hT, dis, out);
}

// Round 8
// 245.120 us; speedup vs baseline: 1.0473x; 1.0473x over previous
//
#include <hip/hip_runtime.h>
#include <hip/hip_bf16.h>

// GCN layer: out[b,n,o] = dis[b,n] * sum_m adj[b,n,m] * dis[b,m] * (x[b,m,:]@W[o,:] + bias[o])
//
// R15: exact revert to R11 (best verified: 244.1us). R13/R14 lesson: NT stores
// race with the harness's dirty-in-L2 poison fills (nt bypasses L2; later
// eviction of stale poison overwrites HBM) -> intermittent post-timing
// corruption. NT hints dropped entirely.
// Structure: K12 fuses degree (blocks 256..) with projection (blocks 0..255,
// no dis fold -> independent of degree). K3 = 64x128/ctile, BK=128
// barrier-amortized, A staged from f32 adj (L3-hot) with dis[b,m] folded in
// f32 before RNE->bf16; B staged via gl_lds16 from bf16 hT.

#define BATCH 8
#define NN    2048
#define DIN   256
#define DOUT  256
#define RTOT  (BATCH * NN)   // 16384
#define HP    (RTOT + 32)    // 16416 padded hT row stride (elems)

typedef short  bf16x8  __attribute__((ext_vector_type(8)));
typedef short  short4v __attribute__((ext_vector_type(4)));
typedef float  f32x4   __attribute__((ext_vector_type(4)));

__device__ __forceinline__ short f2bf(float f) {
    union { float f; unsigned u; } v; v.f = f;
    unsigned r = v.u + 0x7fffu + ((v.u >> 16) & 1u);   // RNE
    return (short)(r >> 16);
}

__device__ __forceinline__ void gl_lds16(const unsigned short* g, unsigned short* l) {
    __builtin_amdgcn_global_load_lds(
        (const __attribute__((address_space(1))) unsigned int*)g,
        (__attribute__((address_space(3))) unsigned int*)l, 16, 0, 0);
}

// ---------------- K12: blocks 0..255 = projection (no dis), 256.. = degrees ----------------
__global__ __launch_bounds__(256) void k_deg_proj(const float* __restrict__ adj,
                                                  const float* __restrict__ x,
                                                  const float* __restrict__ W,
                                                  const float* __restrict__ bias,
                                                  float* __restrict__ dis,
                                                  unsigned short* __restrict__ hT) {
    const int tid = threadIdx.x;

    if (blockIdx.x < 256) {
        // ---- projection part: hT[o, r] = bf16((x@W^T)[r,o] + b[o]), padded rows ----
        const int bid = blockIdx.x;
        const int mt  = bid >> 7;         // 0..1   (o-tile of 128)
        const int nt  = bid & 127;        // 0..127 (r-tile of 128)
        const int w = tid >> 6, lane = tid & 63;
        const int wr = w >> 1, wc = w & 1;
        const int l16 = lane & 15, quad = lane >> 4;

        __shared__ short As[128][32];
        __shared__ short Bs[128][32];

        f32x4 acc[4][4];
#pragma unroll
        for (int i = 0; i < 4; i++)
#pragma unroll
            for (int j = 0; j < 4; j++) acc[i][j] = (f32x4){0.f, 0.f, 0.f, 0.f};

        const float4* Wf4 = (const float4*)(W + (size_t)mt * 128 * DIN);
        const float4* Xf4 = (const float4*)(x + (size_t)nt * 128 * DIN);

        for (int kk = 0; kk < DIN / 32; kk++) {
            const int k0 = kk * 32;
            __syncthreads();
#pragma unroll
            for (int it = 0; it < 4; it++) {
                int idx = tid + it * 256;
                int r = idx >> 3, c = idx & 7;
                float4 va = Wf4[(size_t)r * (DIN / 4) + (k0 >> 2) + c];
                float4 vb = Xf4[(size_t)r * (DIN / 4) + (k0 >> 2) + c];
                short4v sa = { f2bf(va.x), f2bf(va.y), f2bf(va.z), f2bf(va.w) };
                short4v sb = { f2bf(vb.x), f2bf(vb.y), f2bf(vb.z), f2bf(vb.w) };
                *(short4v*)&As[r][c * 4] = sa;
                *(short4v*)&Bs[r][c * 4] = sb;
            }
            __syncthreads();
            bf16x8 af[4], bfv[4];
#pragma unroll
            for (int i = 0; i < 4; i++) af[i]  = *(bf16x8*)&As[wr * 64 + i * 16 + l16][quad * 8];
#pragma unroll
            for (int j = 0; j < 4; j++) bfv[j] = *(bf16x8*)&Bs[wc * 64 + j * 16 + l16][quad * 8];
#pragma unroll
            for (int i = 0; i < 4; i++)
#pragma unroll
                for (int j = 0; j < 4; j++)
                    acc[i][j] = __builtin_amdgcn_mfma_f32_16x16x32_bf16(af[i], bfv[j], acc[i][j], 0, 0, 0);
        }

#pragma unroll
        for (int i = 0; i < 4; i++) {
            const int orow_base = mt * 128 + wr * 64 + i * 16 + quad * 4;
#pragma unroll
            for (int r = 0; r < 4; r++) {
                const int orow = orow_base + r;
                const float bb = bias[orow];
#pragma unroll
                for (int j = 0; j < 4; j++) {
                    const int col = nt * 128 + wc * 64 + j * 16 + l16;
                    float v = acc[i][j][r] + bb;               // dis NOT folded here
                    hT[(size_t)orow * HP + col] = (unsigned short)f2bf(v);
                }
            }
        }
    } else {
        // ---- degree part: dis[row] = rsqrt(rowsum - diag); order identical to R10 ----
        const int row = blockIdx.x - 256;           // 0..16383
        const int n = row & (NN - 1);
        const float4* rp4 = (const float4*)(adj + (size_t)row * NN);

        float s = 0.f;
#pragma unroll
        for (int i = 0; i < 2; i++) {
            float4 v = rp4[tid + i * 256];
            s += (v.x + v.y) + (v.z + v.w);
        }
#pragma unroll
        for (int off = 32; off; off >>= 1) s += __shfl_down(s, off);
        __shared__ float red[4];
        if ((tid & 63) == 0) red[tid >> 6] = s;
        __syncthreads();
        if (tid == 0) {
            float tot  = (red[0] + red[1]) + (red[2] + red[3]);
            float diag = ((const float*)rp4)[n];
            dis[row]   = rsqrtf(tot - diag);
        }
    }
}

// ---------------- K3: out = dis[n] * ((adj .* dis_m) @ hT), BK=128 single-buffer ----------------
// Per batch: M=2048(n), K=2048(m), N=256(o). Block tile 64x128; 16 groups of BK=128
// (4 sub-windows of 32). Grid 512 = 2 blocks/CU: bx&7=batch (XCD L2 affinity),
// (bx>>3)&31=mtile, bx>>8=ctile (pair on same XCD dedups adj reads in L2).
// A staged from adj f32 (L3-hot) with dis[b,m] folded in f32 before RNE->bf16;
// dis slice is L1-hot (8KB/batch, lane-broadcast). B staged via gl_lds16 from
// bf16 hT. One drain per group.
__global__ __launch_bounds__(256, 2) void k_main(const float* __restrict__ adj,
                                                 const unsigned short* __restrict__ hT,
                                                 const float* __restrict__ dis,
                                                 float* __restrict__ out) {
    const int bx    = blockIdx.x;
    const int b     = bx & 7;
    const int mtile = (bx >> 3) & 31;
    const int ctile = bx >> 8;            // 0..1
    const int n0    = mtile * 64;
    const int tid  = threadIdx.x;
    const int w    = tid >> 6, lane = tid & 63;
    const int l16  = lane & 15, quad = lane >> 4;
    const int lr   = lane >> 2;           // 0..15 (staging row-within-group)
    const int lc   = (lane & 3) * 8;      // 0,8,16,24 (staging elem offset)

    __shared__ short As[4][64][32];       // 16 KB: 4 sub-windows of adj rows(n) x 32k
    __shared__ short Bs[4][128][32];      // 32 KB: 4 sub-windows of hT rows(o) x 32k

    const float* disb = dis + (size_t)b * NN;
    // A source: adj row (b*NN + n0 + w*16 + lr), elem offset lc; as float4*
    const float4* agf4 = (const float4*)(adj + (size_t)(b * NN + n0 + w * 16 + lr) * NN + lc);
    const unsigned short* bgp0 = hT + (size_t)(ctile * 128 + w * 32 + lr) * HP + b * NN + lc;
    const unsigned short* bgp1 = bgp0 + (size_t)16 * HP;

    f32x4 acc[4][2];
#pragma unroll
    for (int i = 0; i < 4; i++)
#pragma unroll
        for (int j = 0; j < 2; j++) acc[i][j] = (f32x4){0.f, 0.f, 0.f, 0.f};

    for (int g = 0; g < NN / 128; g++) {          // 16 groups
        // B: 8 async gl_lds16 per thread (issue first, fly during A path)
#pragma unroll
        for (int s = 0; s < 4; s++) {
            const int ko = g * 128 + s * 32;
            gl_lds16(bgp0 + ko, (unsigned short*)&Bs[s][w * 32][0]);
            gl_lds16(bgp1 + ko, (unsigned short*)&Bs[s][w * 32 + 16][0]);
        }
        // A: 8 float4 f32 loads (L3-hot) + dis fold (L1-hot) -> RNE -> 16B ds_write
        float4 av0[4], av1[4];
#pragma unroll
        for (int s = 0; s < 4; s++) {
            av0[s] = agf4[g * 32 + s * 8];
            av1[s] = agf4[g * 32 + s * 8 + 1];
        }
#pragma unroll
        for (int s = 0; s < 4; s++) {
            const float* dp = disb + g * 128 + s * 32 + lc;
            float4 dv0 = *(const float4*)dp;
            float4 dv1 = *(const float4*)(dp + 4);
            bf16x8 pk = { f2bf(av0[s].x * dv0.x), f2bf(av0[s].y * dv0.y),
                          f2bf(av0[s].z * dv0.z), f2bf(av0[s].w * dv0.w),
                          f2bf(av1[s].x * dv1.x), f2bf(av1[s].y * dv1.y),
                          f2bf(av1[s].z * dv1.z), f2bf(av1[s].w * dv1.w) };
            *(bf16x8*)&As[s][w * 16 + lr][lc] = pk;
        }
        __syncthreads();   // drain staging once per 128-K of work
        // Consume: 32 MFMA + 24 ds_read_b128 per wave.
#pragma unroll
        for (int s = 0; s < 4; s++) {
            bf16x8 af[4], bfv[2];
#pragma unroll
            for (int i = 0; i < 4; i++) af[i]  = *(bf16x8*)&As[s][i * 16 + l16][quad * 8];
#pragma unroll
            for (int j = 0; j < 2; j++) bfv[j] = *(bf16x8*)&Bs[s][w * 32 + j * 16 + l16][quad * 8];
#pragma unroll
            for (int i = 0; i < 4; i++)
#pragma unroll
                for (int j = 0; j < 2; j++)
                    acc[i][j] = __builtin_amdgcn_mfma_f32_16x16x32_bf16(af[i], bfv[j], acc[i][j], 0, 0, 0);
        }
        __syncthreads();   // all ds_reads retired before restage
    }

#pragma unroll
    for (int i = 0; i < 4; i++) {
#pragma unroll
        for (int r = 0; r < 4; r++) {
            const int nrow = n0 + i * 16 + quad * 4 + r;
            const float dn = disb[nrow];
#pragma unroll
            for (int j = 0; j < 2; j++) {
                const int ocol = ctile * 128 + w * 32 + j * 16 + l16;
                out[((size_t)b * NN + nrow) * DOUT + ocol] = dn * acc[i][j][r];
            }
        }
    }
}

extern "C" void kernel_launch(void* const* d_in, const int* in_sizes, int n_in,
                              void* d_out, int out_size, void* d_ws, size_t ws_size,
                              hipStream_t stream) {
    const float* x    = (const float*)d_in[0];
    const float* adj  = (const float*)d_in[1];
    const float* W    = (const float*)d_in[2];
    const float* bias = (const float*)d_in[3];
    float* out = (float*)d_out;

    float* dis = (float*)d_ws;                                             // 64 KB
    unsigned short* hT  = (unsigned short*)((char*)d_ws + 65536);          // 256*16416*2 = 8.4 MB

    k_deg_proj<<<256 + RTOT, 256, 0, stream>>>(adj, x, W, bias, dis, hT);
    k_main<<<512, 256, 0, stream>>>(adj, hT, dis, out);
}